// Round 8
// baseline (492.338 us; speedup 1.0000x reference)
//
#include <hip/hip_runtime.h>
#include <cstdint>

#define BH  16
#define SEQ 2048
#define DIM 64
#define OUT_ELEMS (BH*SEQ*DIM)   // 2097152 floats; attn follows at this offset

typedef float f32x4 __attribute__((ext_vector_type(4)));
typedef float f32x2 __attribute__((ext_vector_type(2)));
typedef short bf16x8 __attribute__((ext_vector_type(8)));
typedef unsigned short u16;
typedef unsigned short u16x4 __attribute__((ext_vector_type(4)));

#define MFMA16 __builtin_amdgcn_mfma_f32_16x16x32_bf16

// ---- fallback-kernel LDS partition (kB_old) ----
#define SROW      2052
#define VTM_OFF   (16*SROW)
#define TL_OFF    (VTM_OFF + 4352)
#define QS_OFF    (TL_OFF + 1024)
#define RED_OFF   (QS_OFF + 1024)
#define LDS_FLOATS (RED_OFF + 160)
#define LDS_BYTES  (LDS_FLOATS*4)

__device__ __forceinline__ u16 f2bf(float x){            // RNE f32->bf16
  uint32_t u = __float_as_uint(x);
  return (u16)((u + 0x7fffu + ((u>>16)&1u)) >> 16);
}
__device__ __forceinline__ void split8(f32x4 a, f32x4 b, bf16x8& hi, bf16x8& lo){
  float v[8] = {a.x,a.y,a.z,a.w,b.x,b.y,b.z,b.w};
  #pragma unroll
  for (int i=0;i<8;i++){
    uint32_t u  = __float_as_uint(v[i]);
    uint32_t hb = u & 0xffff0000u;
    hi[i] = (short)(hb>>16);
    lo[i] = (short)f2bf(v[i] - __uint_as_float(hb));
  }
}
__device__ __forceinline__ bf16x8 pack8(f32x4 a, f32x4 b){
  bf16x8 r;
  r[0]=(short)f2bf(a.x); r[1]=(short)f2bf(a.y); r[2]=(short)f2bf(a.z); r[3]=(short)f2bf(a.w);
  r[4]=(short)f2bf(b.x); r[5]=(short)f2bf(b.y); r[6]=(short)f2bf(b.z); r[7]=(short)f2bf(b.w);
  return r;
}

// ---------------- Kernel A1: partial M = k^T q (per batch, per 128-row chunk) ------
__global__ __launch_bounds__(256) void kA1(const float* __restrict__ kk,
                                           const float* __restrict__ qq,
                                           float* __restrict__ part){
  __shared__ __align__(16) float kl[64][68];
  __shared__ __align__(16) float ql[64][68];
  const int b   = blockIdx.y;
  const int ch  = blockIdx.x;
  const int tid = threadIdx.x;
  const int j     = tid & 63;
  const int ibase = (tid >> 6) * 16;   // wave-uniform
  const int lrow  = tid >> 2;
  const int lcol  = (tid & 3) * 16;
  const float* kb = kk + (size_t)b*SEQ*DIM;
  const float* qb = qq + (size_t)b*SEQ*DIM;
  float acc[16];
  #pragma unroll
  for (int i=0;i<16;i++) acc[i]=0.f;
  for (int sub=0; sub<2; ++sub){
    const int l0 = ch*128 + sub*64;
    const f32x4* ks = (const f32x4*)(kb + (size_t)(l0+lrow)*DIM + lcol);
    const f32x4* qs = (const f32x4*)(qb + (size_t)(l0+lrow)*DIM + lcol);
    f32x4 kv[4], qv[4];
    #pragma unroll
    for (int i=0;i<4;i++){ kv[i]=ks[i]; qv[i]=qs[i]; }
    __syncthreads();
    #pragma unroll
    for (int i=0;i<4;i++){
      *(f32x4*)&kl[lrow][lcol+4*i] = kv[i];
      *(f32x4*)&ql[lrow][lcol+4*i] = qv[i];
    }
    __syncthreads();
    for (int t=0; t<64; ++t){
      const float qv1 = ql[t][j];
      const f32x4 k0 = *(const f32x4*)&kl[t][ibase];
      const f32x4 k1 = *(const f32x4*)&kl[t][ibase+4];
      const f32x4 k2 = *(const f32x4*)&kl[t][ibase+8];
      const f32x4 k3 = *(const f32x4*)&kl[t][ibase+12];
      acc[0]+=k0.x*qv1; acc[1]+=k0.y*qv1; acc[2]+=k0.z*qv1; acc[3]+=k0.w*qv1;
      acc[4]+=k1.x*qv1; acc[5]+=k1.y*qv1; acc[6]+=k1.z*qv1; acc[7]+=k1.w*qv1;
      acc[8]+=k2.x*qv1; acc[9]+=k2.y*qv1; acc[10]+=k2.z*qv1; acc[11]+=k2.w*qv1;
      acc[12]+=k3.x*qv1; acc[13]+=k3.y*qv1; acc[14]+=k3.z*qv1; acc[15]+=k3.w*qv1;
    }
  }
  float* pp = part + (size_t)(b*16+ch)*4096;
  #pragma unroll
  for (int ii=0; ii<16; ++ii)
    pp[(ibase+ii)*64 + j] = acc[ii];
}

// ---------------- Kernel A2: reduce partials, fold 1/temper^2 ----------------------
__global__ __launch_bounds__(256) void kA2(const float* __restrict__ part,
                                           float* __restrict__ M){
  const int idx = blockIdx.x*256 + threadIdx.x;
  const int b = idx >> 12, o = idx & 4095;
  float s = 0.f;
  #pragma unroll
  for (int ch=0; ch<16; ++ch)
    s += part[(size_t)(b*16+ch)*4096 + o];
  M[(size_t)b*4096 + o] = s * (1.0f/64.0f);
}

// ---------------- Kernel P: precondition operands ---------------------------------
// vT copy-out is PERMUTED within each 32-col group to match kB9's register-direct
// PV A-frag slot mapping: slot s -> col ((s>>2)&1)*16 + (s>>3)*4 + (s&3).
__global__ __launch_bounds__(512) void kP(const float* __restrict__ pos,
                                          const float* __restrict__ v,
                                          u16* __restrict__ posH,
                                          u16* __restrict__ posL,
                                          u16* __restrict__ vTg){
  __shared__ u16 vt[64][136];
  const int b   = blockIdx.y;
  const int ch  = blockIdx.x;            // 128-row chunk
  const int tid = threadIdx.x;
  // ---- pos hi/lo planes for 128 rows ----
  {
    const f32x4* pb = (const f32x4*)(pos + (size_t)b*SEQ*DIM + (size_t)ch*128*DIM);
    u16* pH = posH + (size_t)b*SEQ*DIM + (size_t)ch*128*DIM;
    u16* pL = posL + (size_t)b*SEQ*DIM + (size_t)ch*128*DIM;
    #pragma unroll
    for (int i=0;i<4;i++){
      const int idx = i*512 + tid;
      const f32x4 x = pb[idx];
      const float xs[4] = {x.x,x.y,x.z,x.w};
      u16x4 h, l;
      #pragma unroll
      for (int jj=0;jj<4;jj++){
        uint32_t u  = __float_as_uint(xs[jj]);
        uint32_t hb = u & 0xffff0000u;
        h[jj] = (u16)(hb>>16);
        l[jj] = f2bf(xs[jj] - __uint_as_float(hb));
      }
      *(u16x4*)&pH[idx*4] = h;
      *(u16x4*)&pL[idx*4] = l;
    }
  }
  // ---- v[ch*128..+128)[64] -> vt[d][c] bf16 (register transpose) ----
  {
    const float* vb = v + (size_t)b*SEQ*DIM;
    const int c4 = (tid & 31)*4;
    const int d4 = (tid >> 5)*4;
    const int cg = ch*128 + c4;
    f32x4 r0v = *(const f32x4*)(vb + (size_t)(cg  )*DIM + d4);
    f32x4 r1v = *(const f32x4*)(vb + (size_t)(cg+1)*DIM + d4);
    f32x4 r2v = *(const f32x4*)(vb + (size_t)(cg+2)*DIM + d4);
    f32x4 r3v = *(const f32x4*)(vb + (size_t)(cg+3)*DIM + d4);
    const float rr[4][4] = {{r0v.x,r1v.x,r2v.x,r3v.x},
                            {r0v.y,r1v.y,r2v.y,r3v.y},
                            {r0v.z,r1v.z,r2v.z,r3v.z},
                            {r0v.w,r1v.w,r2v.w,r3v.w}};
    #pragma unroll
    for (int dd=0; dd<4; ++dd){
      u16x4 pk;
      pk[0]=f2bf(rr[dd][0]); pk[1]=f2bf(rr[dd][1]);
      pk[2]=f2bf(rr[dd][2]); pk[3]=f2bf(rr[dd][3]);
      *(u16x4*)&vt[d4+dd][c4] = pk;
    }
  }
  __syncthreads();
  // ---- permuted copy-out: vTg[b][d][slot], slot->col permutation per 32-group ----
  {
    const int d    = tid >> 3;           // 0..63
    const int roff = (tid & 7)*16;       // 0..112
    u16* dst = vTg + (size_t)b*DIM*SEQ + (size_t)d*SEQ + ch*128 + roff;
    #pragma unroll
    for (int kq=0; kq<4; ++kq){
      const int s0   = roff + kq*4;
      const int sl   = s0 & 31;
      const int csrc = (s0 & ~31) + ((sl>>2)&1)*16 + (sl>>3)*4;
      *(u16x4*)(dst + kq*4) = *(const u16x4*)&vt[d][csrc];
    }
  }
}

// ---------------- Kernel B v9: swapped-operand logits, register-direct PV ---------
// grid 2048, 512 threads, (512,4) = 128-reg budget. Logit MFMAs computed with
// operands SWAPPED (pos as A, T as B) so lane l16 holds q-row l16's columns ->
// PV A-frags come straight from registers (no LDS bounce, no fences). The attn
// store bounce remains (clean full-line NT stores) but is off the MFMA path.
// vT is consumed in kP's permuted slot order. 3 barriers per block.
#define BSTR 36                          // Buf row stride (floats)

__global__ __launch_bounds__(512,4) void kB9(const float* __restrict__ q,
                                             const float* __restrict__ M,
                                             const u16* __restrict__ posH,
                                             const u16* __restrict__ posL,
                                             const u16* __restrict__ vTg,
                                             float* __restrict__ outp,
                                             float* __restrict__ attn){
  __shared__ __align__(16) float Tl[16*68];                 //  4352 B
  __shared__ __align__(16) float Buf[8*16*BSTR];            // 18432 B
  __shared__ __align__(16) float Pp[8*16*68];               // 34816 B
  __shared__ float red_m[128], red_s[128];

  const int blk  = blockIdx.x;
  const int xcd  = blk & 7;
  const int idx  = blk >> 3;              // 0..255
  const int b    = xcd*2 + (idx & 1);     // batch pinned to XCD for L2 locality
  const int task = idx >> 1;              // 0..127
  const int r0   = task*16;
  const int tid  = threadIdx.x;
  const int lane = tid & 63;
  const int w    = tid >> 6;              // 0..7
  const int quad = lane >> 4;
  const int l16  = lane & 15;

  const float* qb  = q    + (size_t)b*SEQ*DIM;
  const float* Mb  = M    + (size_t)b*4096;
  const u16*   pHb = posH + (size_t)b*SEQ*DIM;
  const u16*   pLb = posL + (size_t)b*SEQ*DIM;
  const u16*   vTb = vTg  + (size_t)b*SEQ*DIM;

  // ---- T[16][64] = q[r0..r0+16) * M (reads from L2) ----
  {
    const int r = tid >> 5;
    const int e = tid & 31;
    const float* qr = qb + (size_t)(r0+r)*DIM;
    float a0=0.f, a1=0.f;
    #pragma unroll 8
    for (int d=0; d<64; ++d){
      const float qd = qr[d];
      a0 += qd * Mb[d*64 + e];
      a1 += qd * Mb[d*64 + e + 32];
    }
    Tl[r*68 + e]      = a0;
    Tl[r*68 + e + 32] = a1;
  }
  __syncthreads();                                          // barrier 1

  // ---- T-frags (hi/lo) for both k-halves; same lane layout as before ----
  bf16x8 Th[2], Tlo[2];
  #pragma unroll
  for (int h=0; h<2; ++h){
    const float* ts = &Tl[l16*68 + h*32 + quad*8];
    split8(*(const f32x4*)ts, *(const f32x4*)(ts+4), Th[h], Tlo[h]);
  }

  // ---- logits, SWAPPED: D = pos_tile * T^T -> lane l16 = q-row l16,
  //      reg i of tile tt = column w*256 + tt*16 + quad*4 + i ----
  f32x4 A[16];
  #pragma unroll
  for (int tt=0; tt<16; ++tt){
    const int c0 = w*256 + tt*16;
    const size_t pbase = (size_t)(c0 + l16)*DIM + quad*8;
    const bf16x8 Ph0 = *(const bf16x8*)&pHb[pbase];
    const bf16x8 Pl0 = *(const bf16x8*)&pLb[pbase];
    const bf16x8 Ph1 = *(const bf16x8*)&pHb[pbase + 32];
    const bf16x8 Pl1 = *(const bf16x8*)&pLb[pbase + 32];
    f32x4 acc = {0.f,0.f,0.f,0.f};
    acc = MFMA16(Ph0, Th[0],  acc, 0,0,0);
    acc = MFMA16(Ph0, Tlo[0], acc, 0,0,0);
    acc = MFMA16(Pl0, Th[0],  acc, 0,0,0);
    acc = MFMA16(Ph1, Th[1],  acc, 0,0,0);
    acc = MFMA16(Ph1, Tlo[1], acc, 0,0,0);
    acc = MFMA16(Pl1, Th[1],  acc, 0,0,0);
    A[tt] = acc;
  }

  // ---- softmax: lane owns ONE row (l16); 64 values per lane ----
  float mown;
  {
    f32x4 mv = A[0];
    #pragma unroll
    for (int tt=1; tt<16; ++tt){
      mv.x = fmaxf(mv.x, A[tt].x); mv.y = fmaxf(mv.y, A[tt].y);
      mv.z = fmaxf(mv.z, A[tt].z); mv.w = fmaxf(mv.w, A[tt].w);
    }
    mown = fmaxf(fmaxf(mv.x,mv.y), fmaxf(mv.z,mv.w));
  }
  float sown = 0.f;
  #pragma unroll
  for (int tt=0; tt<16; ++tt){
    #pragma unroll
    for (int i=0;i<4;++i){
      const float e = __expf(A[tt][i] - mown);
      A[tt][i] = e;
      sown += e;
    }
  }
  // combine across the 4 quad-groups holding the same row
  float mw = mown, sw = sown;
  #pragma unroll
  for (int mk=16; mk<=32; mk<<=1){
    const float mo = __shfl_xor(mw, mk, 64);
    const float so = __shfl_xor(sw, mk, 64);
    const float t  = fmaxf(mw, mo);
    sw = sw*__expf(mw-t) + so*__expf(mo-t);
    mw = t;
  }
  if (lane < 16){
    red_m[w*16 + lane] = mw;
    red_s[w*16 + lane] = sw;
  }
  __syncthreads();                                          // barrier 2
  // parallel redundant global combine: every thread for its own row l16
  {
    float mg = red_m[l16], sg = red_s[l16];
    #pragma unroll
    for (int w2=1; w2<8; ++w2){
      const float mo = red_m[w2*16 + l16], so = red_s[w2*16 + l16];
      const float t  = fmaxf(mg, mo);
      sg = sg*__expf(mg-t) + so*__expf(mo-t);
      mg = t;
    }
    const float cf = __expf(mown - mg) * (1.0f/sg);
    #pragma unroll
    for (int tt=0; tt<16; ++tt){
      A[tt].x *= cf; A[tt].y *= cf; A[tt].z *= cf; A[tt].w *= cf;
    }
  }

  // ---- fused PV (register-direct A-frags) + coalesced attn store via Buf ----
  f32x4 pa0={0.f,0.f,0.f,0.f}, pa1=pa0, pa2=pa0, pa3=pa0;
  float* bw = &Buf[w*16*BSTR];
  const int srow = lane >> 3;              // 0..7
  const int scol = (lane & 7)*4;           // 0..28
  float* abase = attn + ((size_t)b*SEQ + r0)*(size_t)SEQ;
  #pragma unroll
  for (int pr=0; pr<8; ++pr){
    const int c0p = w*256 + pr*32;
    // deposit normalized 16x32 chunk: row l16, cols quad*4.. and 16+quad*4..
    *(f32x4*)&bw[l16*BSTR + quad*4]      = A[2*pr];
    *(f32x4*)&bw[l16*BSTR + 16 + quad*4] = A[2*pr+1];
    // PV A-frag straight from registers (slot order matches kP's permuted vT)
    const bf16x8 Af = pack8(A[2*pr], A[2*pr+1]);
    const size_t k0 = (size_t)c0p + quad*8;
    const bf16x8 B0 = *(const bf16x8*)&vTb[(size_t)(l16     )*SEQ + k0];
    const bf16x8 B1 = *(const bf16x8*)&vTb[(size_t)(l16 + 16)*SEQ + k0];
    const bf16x8 B2 = *(const bf16x8*)&vTb[(size_t)(l16 + 32)*SEQ + k0];
    const bf16x8 B3 = *(const bf16x8*)&vTb[(size_t)(l16 + 48)*SEQ + k0];
    pa0 = MFMA16(Af, B0, pa0, 0,0,0);
    pa1 = MFMA16(Af, B1, pa1, 0,0,0);
    pa2 = MFMA16(Af, B2, pa2, 0,0,0);
    pa3 = MFMA16(Af, B3, pa3, 0,0,0);
    // coalesced attn store (same-wave DS in-order; compiler inserts lgkmcnt)
    const f32x4 st0 = *(const f32x4*)&bw[srow*BSTR + scol];
    const f32x4 st1 = *(const f32x4*)&bw[(srow+8)*BSTR + scol];
    __builtin_nontemporal_store(st0, (f32x4*)(abase + (size_t)srow*SEQ     + c0p + scol));
    __builtin_nontemporal_store(st1, (f32x4*)(abase + (size_t)(srow+8)*SEQ + c0p + scol));
  }

  // ---- deposit per-wave PV partials, reduce across the 8 k-chunks ----
  {
    float* pp = &Pp[w*16*68];
    #pragma unroll
    for (int i=0;i<4;++i){
      pp[(quad*4+i)*68 +  0 + l16] = pa0[i];
      pp[(quad*4+i)*68 + 16 + l16] = pa1[i];
      pp[(quad*4+i)*68 + 32 + l16] = pa2[i];
      pp[(quad*4+i)*68 + 48 + l16] = pa3[i];
    }
  }
  __syncthreads();                                          // barrier 3
  {
    const int o = tid*2;
    const int m = o >> 6;
    const int d = o & 63;
    float sa=0.f, sb=0.f;
    #pragma unroll
    for (int kk=0; kk<8; ++kk){
      const float* pr2 = &Pp[kk*16*68 + m*68 + d];
      sa += pr2[0];
      sb += pr2[1];
    }
    f32x2 res; res.x = sa; res.y = sb;
    *(f32x2*)(outp + ((size_t)b*SEQ + r0 + m)*DIM + d) = res;
  }
}

// ---------------- Kernel B v1 (fallback when workspace is too small) --------------
__global__ __launch_bounds__(512,2) void kB_old(const float* __restrict__ q,
                                                const float* __restrict__ pos,
                                                const float* __restrict__ v,
                                                const float* __restrict__ M,
                                                float* __restrict__ outp,
                                                float* __restrict__ attn){
  extern __shared__ __align__(16) float smem[];
  float* S    = smem;
  float* VTM  = smem + VTM_OFF;
  u16*   vT   = (u16*)VTM;
  float* Tl   = smem + TL_OFF;
  float* qs   = smem + QS_OFF;
  float* red  = smem + RED_OFF;
  float* mrow = red + 128;
  float* linv = mrow + 16;

  const int blk   = blockIdx.x;
  const int xcd   = blk & 7;
  const int slot  = blk >> 3;
  const int b     = xcd*2 + (slot & 1);
  const int bslot = slot >> 1;
  const int tid   = threadIdx.x;
  const int lane  = tid & 63;
  const int w     = tid >> 6;
  const int quad  = lane >> 4;
  const int l16   = lane & 15;

  const float* pb = pos + (size_t)b*SEQ*DIM;
  const float* vb = v   + (size_t)b*SEQ*DIM;
  const float* qb = q   + (size_t)b*SEQ*DIM;
  const float* Mb = M   + (size_t)b*4096;

  for (int t = 0; t < 8; ++t){
    const int r0 = (bslot*8 + t) * 16;
    __syncthreads();
    {
      const f32x4* Mg = (const f32x4*)Mb;
      f32x4* Md = (f32x4*)VTM;
      Md[tid]     = Mg[tid];
      Md[tid+512] = Mg[tid+512];
      if (tid < 256)
        ((f32x4*)qs)[tid] = ((const f32x4*)(qb + (size_t)r0*DIM))[tid];
    }
    __syncthreads();
    {
      const int r = tid >> 5;
      const int e = tid & 31;
      float a0 = 0.f, a1 = 0.f;
      #pragma unroll 8
      for (int d=0; d<64; ++d){
        const float qd = qs[r*64 + d];
        a0 += qd * VTM[d*64 + e];
        a1 += qd * VTM[d*64 + e + 32];
      }
      Tl[r*64 + e]      = a0;
      Tl[r*64 + e + 32] = a1;
    }
    __syncthreads();
    bf16x8 Ah[2], Al[2];
    #pragma unroll
    for (int h=0; h<2; ++h){
      const float* ts = &Tl[l16*64 + h*32 + quad*8];
      split8(*(const f32x4*)ts, *(const f32x4*)(ts+4), Ah[h], Al[h]);
    }
    #pragma unroll 2
    for (int tt=0; tt<16; ++tt){
      const int c0 = w*256 + tt*16;
      const float* pr = pb + (size_t)(c0 + l16)*DIM + quad*8;
      f32x4 p0 = *(const f32x4*)pr;
      f32x4 p1 = *(const f32x4*)(pr+4);
      f32x4 p2 = *(const f32x4*)(pr+32);
      f32x4 p3 = *(const f32x4*)(pr+36);
      bf16x8 Bh0, Bl0, Bh1, Bl1;
      split8(p0, p1, Bh0, Bl0);
      split8(p2, p3, Bh1, Bl1);
      f32x4 acc = {0.f,0.f,0.f,0.f};
      acc = MFMA16(Ah[0], Bh0, acc, 0,0,0);
      acc = MFMA16(Al[0], Bh0, acc, 0,0,0);
      acc = MFMA16(Ah[0], Bl0, acc, 0,0,0);
      acc = MFMA16(Ah[1], Bh1, acc, 0,0,0);
      acc = MFMA16(Al[1], Bh1, acc, 0,0,0);
      acc = MFMA16(Ah[1], Bl1, acc, 0,0,0);
      #pragma unroll
      for (int i=0;i<4;i++)
        S[(quad*4+i)*SROW + c0 + l16] = acc[i];
    }
    __syncthreads();
    {
      const int r = tid & 15, seg = tid >> 4;
      const f32x4* sr = (const f32x4*)&S[r*SROW + seg*64];
      float m = -3.0e38f;
      #pragma unroll
      for (int i=0;i<16;i++){
        const f32x4 x = sr[i];
        m = fmaxf(m, fmaxf(fmaxf(x.x,x.y), fmaxf(x.z,x.w)));
      }
      m = fmaxf(m, __shfl_xor(m, 16, 64));
      m = fmaxf(m, __shfl_xor(m, 32, 64));
      if (lane < 16) red[w*16 + lane] = m;
    }
    __syncthreads();
    if (tid < 16){
      float m = red[tid];
      #pragma unroll
      for (int w2=1; w2<8; ++w2) m = fmaxf(m, red[w2*16 + tid]);
      mrow[tid] = m;
    }
    __syncthreads();
    {
      const int r = tid & 15, seg = tid >> 4;
      const float mr = mrow[r];
      f32x4* sr = (f32x4*)&S[r*SROW + seg*64];
      float s = 0.f;
      #pragma unroll
      for (int i=0;i<16;i++){
        f32x4 x = sr[i];
        x.x = __expf(x.x - mr); x.y = __expf(x.y - mr);
        x.z = __expf(x.z - mr); x.w = __expf(x.w - mr);
        sr[i] = x;
        s += x.x + x.y + x.z + x.w;
      }
      s += __shfl_xor(s, 16, 64);
      s += __shfl_xor(s, 32, 64);
      if (lane < 16) red[w*16 + lane] = s;
    }
    __syncthreads();
    if (tid < 16){
      float s = red[tid];
      #pragma unroll
      for (int w2=1; w2<8; ++w2) s += red[w2*16 + tid];
      linv[tid] = 1.0f / s;
    }
    __syncthreads();
    {
      const int r  = tid >> 5;
      const int cq = (tid & 31) * 4;
      const float li = linv[r];
      float* ab = attn + ((size_t)b*SEQ + r0 + r)*(size_t)SEQ;
      const float* sr = &S[r*SROW];
      #pragma unroll
      for (int j=0;j<16;++j){
        const int c = cq + 128*j;
        f32x4 val = *(const f32x4*)(sr + c);
        val.x *= li; val.y *= li; val.z *= li; val.w *= li;
        __builtin_nontemporal_store(val, (f32x4*)(ab + c));
      }
    }
    f32x4 pacc0 = {0.f,0.f,0.f,0.f}, pacc1 = {0.f,0.f,0.f,0.f};
    const int kch   = w >> 1;
    const int npair = w & 1;
    for (int vt2=0; vt2<16; ++vt2){
      __syncthreads();
      {
        const int c4 = (tid & 31)*4;
        const int d4 = (tid >> 5)*4;
        const int cg = vt2*128 + c4;
        f32x4 r0v = *(const f32x4*)(vb + (size_t)(cg  )*DIM + d4);
        f32x4 r1v = *(const f32x4*)(vb + (size_t)(cg+1)*DIM + d4);
        f32x4 r2v = *(const f32x4*)(vb + (size_t)(cg+2)*DIM + d4);
        f32x4 r3v = *(const f32x4*)(vb + (size_t)(cg+3)*DIM + d4);
        const float rr[4][4] = {{r0v.x,r1v.x,r2v.x,r3v.x},
                                {r0v.y,r1v.y,r2v.y,r3v.y},
                                {r0v.z,r1v.z,r2v.z,r3v.z},
                                {r0v.w,r1v.w,r2v.w,r3v.w}};
        #pragma unroll
        for (int dd=0; dd<4; ++dd){
          u16x4 pk;
          pk[0]=f2bf(rr[dd][0]); pk[1]=f2bf(rr[dd][1]);
          pk[2]=f2bf(rr[dd][2]); pk[3]=f2bf(rr[dd][3]);
          *(u16x4*)&vT[(d4+dd)*136 + c4] = pk;
        }
      }
      __syncthreads();
      {
        const int cbase = kch*32;
        const float* es = &S[l16*SROW + vt2*128 + cbase + quad*8];
        const bf16x8 Af = pack8(*(const f32x4*)es, *(const f32x4*)(es+4));
        const int n0 = (npair*2)*16 + l16;
        const int n1 = n0 + 16;
        const bf16x8 B0 = *(const bf16x8*)&vT[n0*136 + cbase + quad*8];
        const bf16x8 B1 = *(const bf16x8*)&vT[n1*136 + cbase + quad*8];
        pacc0 = MFMA16(Af, B0, pacc0, 0,0,0);
        pacc1 = MFMA16(Af, B1, pacc1, 0,0,0);
      }
    }
    __syncthreads();
    {
      float* Pf = S;
      #pragma unroll
      for (int i=0;i<4;i++){
        Pf[(w*2+0)*256 + (quad*4+i)*16 + l16] = pacc0[i];
        Pf[(w*2+1)*256 + (quad*4+i)*16 + l16] = pacc1[i];
      }
      pacc0 = (f32x4){0.f,0.f,0.f,0.f};
      pacc1 = (f32x4){0.f,0.f,0.f,0.f};
    }
    __syncthreads();
    {
      const int o = tid*2;
      const int m = o >> 6;
      const int d = o & 63;
      const int nt = d >> 4;
      float s0 = 0.f, s1 = 0.f;
      #pragma unroll
      for (int kk=0; kk<4; ++kk){
        const int sl = (2*kk + (nt>>1))*2 + (nt&1);
        s0 += S[sl*256 + m*16 + (d&15)];
        s1 += S[sl*256 + m*16 + (d&15) + 1];
      }
      const float li = linv[m];
      f32x2 res; res.x = s0*li; res.y = s1*li;
      *(f32x2*)(outp + ((size_t)b*SEQ + r0 + m)*DIM + d) = res;
    }
  }
}

extern "C" void kernel_launch(void* const* d_in, const int* in_sizes, int n_in,
                              void* d_out, int out_size, void* d_ws, size_t ws_size,
                              hipStream_t stream){
  const float* q = (const float*)d_in[0];
  const float* k = (const float*)d_in[1];
  const float* v = (const float*)d_in[2];
  const float* p = (const float*)d_in[3];
  float* out  = (float*)d_out;
  float* attn = out + OUT_ELEMS;          // second tuple element
  float* M    = (float*)d_ws;             // 16*64*64 fp32 = 256 KB
  float* part = attn;                     // M-partials scratch; dead after kA2

  // ws layout: M (256 KB) | posH (4 MB) | posL (4 MB) | vT (4 MB)
  const size_t NEED = 262144 + 3ull*BH*SEQ*DIM*sizeof(u16);  // 12.85 MB

  hipFuncSetAttribute((const void*)kB_old,
                      hipFuncAttributeMaxDynamicSharedMemorySize, LDS_BYTES);

  kA1<<<dim3(16,16), 256, 0, stream>>>(k, q, part);
  kA2<<<dim3(256),   256, 0, stream>>>(part, M);

  if (ws_size >= NEED){
    u16* posH = (u16*)((char*)d_ws + 262144);
    u16* posL = posH + (size_t)BH*SEQ*DIM;
    u16* vTg  = posL + (size_t)BH*SEQ*DIM;
    kP<<<dim3(16,16), 512, 0, stream>>>(p, v, posH, posL, vTg);
    kB9<<<dim3(2048), 512, 0, stream>>>(q, M, posH, posL, vTg, out, attn);
  } else {
    kB_old<<<dim3(256), 512, LDS_BYTES, stream>>>(q, p, v, M, out, attn);
  }
}

// Round 9
// 472.301 us; speedup vs baseline: 1.0424x; 1.0424x over previous
//
#include <hip/hip_runtime.h>
#include <cstdint>

#define BH  16
#define SEQ 2048
#define DIM 64
#define OUT_ELEMS (BH*SEQ*DIM)   // 2097152 floats; attn follows at this offset

typedef float f32x4 __attribute__((ext_vector_type(4)));
typedef float f32x2 __attribute__((ext_vector_type(2)));
typedef short bf16x8 __attribute__((ext_vector_type(8)));
typedef unsigned short u16;
typedef unsigned short u16x4 __attribute__((ext_vector_type(4)));

#define MFMA16 __builtin_amdgcn_mfma_f32_16x16x32_bf16

// ---- fallback-kernel LDS partition (kB_old) ----
#define SROW      2052
#define VTM_OFF   (16*SROW)
#define TL_OFF    (VTM_OFF + 4352)
#define QS_OFF    (TL_OFF + 1024)
#define RED_OFF   (QS_OFF + 1024)
#define LDS_FLOATS (RED_OFF + 160)
#define LDS_BYTES  (LDS_FLOATS*4)

__device__ __forceinline__ u16 f2bf(float x){            // RNE f32->bf16
  uint32_t u = __float_as_uint(x);
  return (u16)((u + 0x7fffu + ((u>>16)&1u)) >> 16);
}
__device__ __forceinline__ void split8(f32x4 a, f32x4 b, bf16x8& hi, bf16x8& lo){
  float v[8] = {a.x,a.y,a.z,a.w,b.x,b.y,b.z,b.w};
  #pragma unroll
  for (int i=0;i<8;i++){
    uint32_t u  = __float_as_uint(v[i]);
    uint32_t hb = u & 0xffff0000u;
    hi[i] = (short)(hb>>16);
    lo[i] = (short)f2bf(v[i] - __uint_as_float(hb));
  }
}
__device__ __forceinline__ bf16x8 pack8(f32x4 a, f32x4 b){
  bf16x8 r;
  r[0]=(short)f2bf(a.x); r[1]=(short)f2bf(a.y); r[2]=(short)f2bf(a.z); r[3]=(short)f2bf(a.w);
  r[4]=(short)f2bf(b.x); r[5]=(short)f2bf(b.y); r[6]=(short)f2bf(b.z); r[7]=(short)f2bf(b.w);
  return r;
}

// ---------------- Kernel A1: partial M = k^T q (per batch, per 128-row chunk) ------
__global__ __launch_bounds__(256) void kA1(const float* __restrict__ kk,
                                           const float* __restrict__ qq,
                                           float* __restrict__ part){
  __shared__ __align__(16) float kl[64][68];
  __shared__ __align__(16) float ql[64][68];
  const int b   = blockIdx.y;
  const int ch  = blockIdx.x;
  const int tid = threadIdx.x;
  const int j     = tid & 63;
  const int ibase = (tid >> 6) * 16;   // wave-uniform
  const int lrow  = tid >> 2;
  const int lcol  = (tid & 3) * 16;
  const float* kb = kk + (size_t)b*SEQ*DIM;
  const float* qb = qq + (size_t)b*SEQ*DIM;
  float acc[16];
  #pragma unroll
  for (int i=0;i<16;i++) acc[i]=0.f;
  for (int sub=0; sub<2; ++sub){
    const int l0 = ch*128 + sub*64;
    const f32x4* ks = (const f32x4*)(kb + (size_t)(l0+lrow)*DIM + lcol);
    const f32x4* qs = (const f32x4*)(qb + (size_t)(l0+lrow)*DIM + lcol);
    f32x4 kv[4], qv[4];
    #pragma unroll
    for (int i=0;i<4;i++){ kv[i]=ks[i]; qv[i]=qs[i]; }
    __syncthreads();
    #pragma unroll
    for (int i=0;i<4;i++){
      *(f32x4*)&kl[lrow][lcol+4*i] = kv[i];
      *(f32x4*)&ql[lrow][lcol+4*i] = qv[i];
    }
    __syncthreads();
    for (int t=0; t<64; ++t){
      const float qv1 = ql[t][j];
      const f32x4 k0 = *(const f32x4*)&kl[t][ibase];
      const f32x4 k1 = *(const f32x4*)&kl[t][ibase+4];
      const f32x4 k2 = *(const f32x4*)&kl[t][ibase+8];
      const f32x4 k3 = *(const f32x4*)&kl[t][ibase+12];
      acc[0]+=k0.x*qv1; acc[1]+=k0.y*qv1; acc[2]+=k0.z*qv1; acc[3]+=k0.w*qv1;
      acc[4]+=k1.x*qv1; acc[5]+=k1.y*qv1; acc[6]+=k1.z*qv1; acc[7]+=k1.w*qv1;
      acc[8]+=k2.x*qv1; acc[9]+=k2.y*qv1; acc[10]+=k2.z*qv1; acc[11]+=k2.w*qv1;
      acc[12]+=k3.x*qv1; acc[13]+=k3.y*qv1; acc[14]+=k3.z*qv1; acc[15]+=k3.w*qv1;
    }
  }
  float* pp = part + (size_t)(b*16+ch)*4096;
  #pragma unroll
  for (int ii=0; ii<16; ++ii)
    pp[(ibase+ii)*64 + j] = acc[ii];
}

// ---------------- Kernel A2: reduce partials, fold 1/temper^2 ----------------------
__global__ __launch_bounds__(256) void kA2(const float* __restrict__ part,
                                           float* __restrict__ M){
  const int idx = blockIdx.x*256 + threadIdx.x;
  const int b = idx >> 12, o = idx & 4095;
  float s = 0.f;
  #pragma unroll
  for (int ch=0; ch<16; ++ch)
    s += part[(size_t)(b*16+ch)*4096 + o];
  M[(size_t)b*4096 + o] = s * (1.0f/64.0f);
}

// ---------------- Kernel P: precondition operands (hi/lo pos planes, vT bf16) -----
__global__ __launch_bounds__(512) void kP(const float* __restrict__ pos,
                                          const float* __restrict__ v,
                                          u16* __restrict__ posH,
                                          u16* __restrict__ posL,
                                          u16* __restrict__ vTg){
  __shared__ u16 vt[64][136];
  const int b   = blockIdx.y;
  const int ch  = blockIdx.x;            // 128-row chunk
  const int tid = threadIdx.x;
  // ---- pos hi/lo planes for 128 rows ----
  {
    const f32x4* pb = (const f32x4*)(pos + (size_t)b*SEQ*DIM + (size_t)ch*128*DIM);
    u16* pH = posH + (size_t)b*SEQ*DIM + (size_t)ch*128*DIM;
    u16* pL = posL + (size_t)b*SEQ*DIM + (size_t)ch*128*DIM;
    #pragma unroll
    for (int i=0;i<4;i++){
      const int idx = i*512 + tid;
      const f32x4 x = pb[idx];
      const float xs[4] = {x.x,x.y,x.z,x.w};
      u16x4 h, l;
      #pragma unroll
      for (int jj=0;jj<4;jj++){
        uint32_t u  = __float_as_uint(xs[jj]);
        uint32_t hb = u & 0xffff0000u;
        h[jj] = (u16)(hb>>16);
        l[jj] = f2bf(xs[jj] - __uint_as_float(hb));
      }
      *(u16x4*)&pH[idx*4] = h;
      *(u16x4*)&pL[idx*4] = l;
    }
  }
  // ---- v[ch*128..+128)[64] -> vt[d][c] bf16 (register transpose) ----
  {
    const float* vb = v + (size_t)b*SEQ*DIM;
    const int c4 = (tid & 31)*4;
    const int d4 = (tid >> 5)*4;
    const int cg = ch*128 + c4;
    f32x4 r0v = *(const f32x4*)(vb + (size_t)(cg  )*DIM + d4);
    f32x4 r1v = *(const f32x4*)(vb + (size_t)(cg+1)*DIM + d4);
    f32x4 r2v = *(const f32x4*)(vb + (size_t)(cg+2)*DIM + d4);
    f32x4 r3v = *(const f32x4*)(vb + (size_t)(cg+3)*DIM + d4);
    const float rr[4][4] = {{r0v.x,r1v.x,r2v.x,r3v.x},
                            {r0v.y,r1v.y,r2v.y,r3v.y},
                            {r0v.z,r1v.z,r2v.z,r3v.z},
                            {r0v.w,r1v.w,r2v.w,r3v.w}};
    #pragma unroll
    for (int dd=0; dd<4; ++dd){
      u16x4 pk;
      pk[0]=f2bf(rr[dd][0]); pk[1]=f2bf(rr[dd][1]);
      pk[2]=f2bf(rr[dd][2]); pk[3]=f2bf(rr[dd][3]);
      *(u16x4*)&vt[d4+dd][c4] = pk;
    }
  }
  __syncthreads();
  // ---- coalesced copy-out: vTg[b][d][k], k contiguous ----
  {
    const int d    = tid >> 3;           // 0..63
    const int roff = (tid & 7)*16;       // 0..112
    u16* dst = vTg + (size_t)b*DIM*SEQ + (size_t)d*SEQ + ch*128 + roff;
    const u16* src = &vt[d][roff];
    #pragma unroll
    for (int kq=0; kq<4; ++kq)
      *(u16x4*)(dst + kq*4) = *(const u16x4*)(src + kq*4);
  }
}

// ---------------- Kernel B v10: v8 structure, CACHED attn stores (no NT) ----------
// Single variable vs v8: attn stores are regular (write-back through L2) instead of
// __builtin_nontemporal_store. Theory: NT streaming stores cap ~1.3 TB/s (observed
// across v2/v4/v8/v9); cached writes coalesce in L2 and drain at >=2 TB/s (v5 data).
#define BSTR 36                          // Buf row stride (floats)

__global__ __launch_bounds__(512,4) void kB10(const float* __restrict__ q,
                                              const float* __restrict__ M,
                                              const u16* __restrict__ posH,
                                              const u16* __restrict__ posL,
                                              const u16* __restrict__ vTg,
                                              float* __restrict__ outp,
                                              float* __restrict__ attn){
  __shared__ __align__(16) float Tl[16*68];                 //  4352 B
  __shared__ __align__(16) float Buf[8*16*BSTR];            // 18432 B
  __shared__ __align__(16) float Pp[8*16*68];               // 34816 B
  __shared__ float red_m[128], red_s[128], mrow[16], linv[16];

  const int blk  = blockIdx.x;
  const int xcd  = blk & 7;
  const int idx  = blk >> 3;              // 0..255
  const int b    = xcd*2 + (idx & 1);     // batch pinned to XCD for L2 locality
  const int task = idx >> 1;              // 0..127
  const int r0   = task*16;
  const int tid  = threadIdx.x;
  const int lane = tid & 63;
  const int w    = tid >> 6;              // 0..7
  const int quad = lane >> 4;
  const int l16  = lane & 15;

  const float* qb  = q    + (size_t)b*SEQ*DIM;
  const float* Mb  = M    + (size_t)b*4096;
  const u16*   pHb = posH + (size_t)b*SEQ*DIM;
  const u16*   pLb = posL + (size_t)b*SEQ*DIM;
  const u16*   vTb = vTg  + (size_t)b*SEQ*DIM;

  // ---- T[16][64] = q[r0..r0+16) * M (reads from L2) ----
  {
    const int r = tid >> 5;
    const int e = tid & 31;
    const float* qr = qb + (size_t)(r0+r)*DIM;
    float a0=0.f, a1=0.f;
    #pragma unroll 8
    for (int d=0; d<64; ++d){
      const float qd = qr[d];
      a0 += qd * Mb[d*64 + e];
      a1 += qd * Mb[d*64 + e + 32];
    }
    Tl[r*68 + e]      = a0;
    Tl[r*68 + e + 32] = a1;
  }
  __syncthreads();                                          // barrier 1

  // ---- A-frags (T hi/lo) for both k-halves ----
  bf16x8 Ah[2], Al[2];
  #pragma unroll
  for (int h=0; h<2; ++h){
    const float* ts = &Tl[l16*68 + h*32 + quad*8];
    split8(*(const f32x4*)ts, *(const f32x4*)(ts+4), Ah[h], Al[h]);
  }

  // ---- logits into registers: wave w covers cols [w*256, w*256+256) ----
  f32x4 A[16];
  #pragma unroll
  for (int tt=0; tt<16; ++tt){
    const int c0 = w*256 + tt*16;
    const size_t pbase = (size_t)(c0 + l16)*DIM + quad*8;
    const bf16x8 Bh0 = *(const bf16x8*)&pHb[pbase];
    const bf16x8 Bl0 = *(const bf16x8*)&pLb[pbase];
    const bf16x8 Bh1 = *(const bf16x8*)&pHb[pbase + 32];
    const bf16x8 Bl1 = *(const bf16x8*)&pLb[pbase + 32];
    f32x4 acc = {0.f,0.f,0.f,0.f};
    acc = MFMA16(Ah[0], Bh0, acc, 0,0,0);
    acc = MFMA16(Al[0], Bh0, acc, 0,0,0);
    acc = MFMA16(Ah[0], Bl0, acc, 0,0,0);
    acc = MFMA16(Ah[1], Bh1, acc, 0,0,0);
    acc = MFMA16(Al[1], Bh1, acc, 0,0,0);
    acc = MFMA16(Ah[1], Bl1, acc, 0,0,0);
    A[tt] = acc;
  }

  // ---- per-lane row stats (rows quad*4+i, exp computed ONCE) ----
  float mloc[4], sloc[4];
  #pragma unroll
  for (int i=0;i<4;++i) mloc[i] = A[0][i];
  #pragma unroll
  for (int tt=1; tt<16; ++tt){
    #pragma unroll
    for (int i=0;i<4;++i) mloc[i] = fmaxf(mloc[i], A[tt][i]);
  }
  #pragma unroll
  for (int i=0;i<4;++i) sloc[i] = 0.f;
  #pragma unroll
  for (int tt=0; tt<16; ++tt){
    #pragma unroll
    for (int i=0;i<4;++i){
      const float e = __expf(A[tt][i] - mloc[i]);
      A[tt][i] = e;
      sloc[i] += e;
    }
  }
  // cross-lane (l16) combine with rescale
  float mc[4], sc[4];
  #pragma unroll
  for (int i=0;i<4;++i){ mc[i]=mloc[i]; sc[i]=sloc[i]; }
  #pragma unroll
  for (int mk=1; mk<16; mk<<=1){
    #pragma unroll
    for (int i=0;i<4;++i){
      const float mo = __shfl_xor(mc[i], mk, 64);
      const float so = __shfl_xor(sc[i], mk, 64);
      const float t  = fmaxf(mc[i], mo);
      sc[i] = sc[i]*__expf(mc[i]-t) + so*__expf(mo-t);
      mc[i] = t;
    }
  }
  if (l16 == 0){
    #pragma unroll
    for (int i=0;i<4;++i){
      red_m[w*16 + quad*4 + i] = mc[i];
      red_s[w*16 + quad*4 + i] = sc[i];
    }
  }
  __syncthreads();                                          // barrier 2
  if (tid < 16){
    float m = red_m[tid], s = red_s[tid];
    #pragma unroll
    for (int w2=1; w2<8; ++w2){
      const float mo = red_m[w2*16 + tid], so = red_s[w2*16 + tid];
      const float t  = fmaxf(m, mo);
      s = s*__expf(m-t) + so*__expf(mo-t);
      m = t;
    }
    mrow[tid] = m;
    linv[tid] = 1.0f/s;
  }
  __syncthreads();                                          // barrier 3

  // ---- normalize in registers: A = exp(x - m_g) * linv ----
  #pragma unroll
  for (int i=0;i<4;++i){
    const float cf = __expf(mloc[i] - mrow[quad*4+i]) * linv[quad*4+i];
    #pragma unroll
    for (int tt=0; tt<16; ++tt) A[tt][i] *= cf;
  }

  // ---- fused attn-store + PV, per 32-col chunk, wave-private Buf, no barriers ----
  f32x4 pa0={0.f,0.f,0.f,0.f}, pa1=pa0, pa2=pa0, pa3=pa0;
  float* bw = &Buf[w*16*BSTR];
  const int srow = lane >> 3;              // 0..7
  const int scol = (lane & 7)*4;           // 0..28
  float* abase = attn + ((size_t)b*SEQ + r0)*(size_t)SEQ;
  #pragma unroll
  for (int pr=0; pr<8; ++pr){
    // deposit 16x32 normalized chunk (cols pr*32..+32 of this wave's span)
    #pragma unroll
    for (int i=0;i<4;++i){
      bw[(quad*4+i)*BSTR      + l16] = A[2*pr  ][i];
      bw[(quad*4+i)*BSTR + 16 + l16] = A[2*pr+1][i];
    }
    // PV B-loads issued BEFORE the DS fence: L2 latency overlaps the bounce.
    const int c0p = w*256 + pr*32;
    const size_t k0 = (size_t)c0p + quad*8;
    const bf16x8 B0 = *(const bf16x8*)&vTb[(size_t)(l16     )*SEQ + k0];
    const bf16x8 B1 = *(const bf16x8*)&vTb[(size_t)(l16 + 16)*SEQ + k0];
    const bf16x8 B2 = *(const bf16x8*)&vTb[(size_t)(l16 + 32)*SEQ + k0];
    const bf16x8 B3 = *(const bf16x8*)&vTb[(size_t)(l16 + 48)*SEQ + k0];
    asm volatile("s_waitcnt lgkmcnt(0)" ::: "memory");
    __builtin_amdgcn_sched_barrier(0);
    // PV A-frag: row l16, k = quad*8..+8
    const f32x4 fa0 = *(const f32x4*)&bw[l16*BSTR + quad*8];
    const f32x4 fa1 = *(const f32x4*)&bw[l16*BSTR + quad*8 + 4];
    const bf16x8 Af = pack8(fa0, fa1);
    const f32x4 st0 = *(const f32x4*)&bw[srow*BSTR + scol];
    const f32x4 st1 = *(const f32x4*)&bw[(srow+8)*BSTR + scol];
    // PV MFMAs first (B-frags have arrived by now), stores after
    pa0 = MFMA16(Af, B0, pa0, 0,0,0);
    pa1 = MFMA16(Af, B1, pa1, 0,0,0);
    pa2 = MFMA16(Af, B2, pa2, 0,0,0);
    pa3 = MFMA16(Af, B3, pa3, 0,0,0);
    // attn store: REGULAR cached stores (the experiment: no NT hint)
    *(f32x4*)(abase + (size_t)srow*SEQ     + c0p + scol) = st0;
    *(f32x4*)(abase + (size_t)(srow+8)*SEQ + c0p + scol) = st1;
    asm volatile("" ::: "memory");        // keep next deposit after this chunk's reads
  }

  // ---- deposit per-wave PV partials, reduce across the 8 k-chunks ----
  {
    float* pp = &Pp[w*16*68];
    #pragma unroll
    for (int i=0;i<4;++i){
      pp[(quad*4+i)*68 +  0 + l16] = pa0[i];
      pp[(quad*4+i)*68 + 16 + l16] = pa1[i];
      pp[(quad*4+i)*68 + 32 + l16] = pa2[i];
      pp[(quad*4+i)*68 + 48 + l16] = pa3[i];
    }
  }
  __syncthreads();                                          // barrier 4
  {
    const int o = tid*2;
    const int m = o >> 6;
    const int d = o & 63;
    float sa=0.f, sb=0.f;
    #pragma unroll
    for (int kk=0; kk<8; ++kk){
      const float* pr2 = &Pp[kk*16*68 + m*68 + d];
      sa += pr2[0];
      sb += pr2[1];
    }
    f32x2 res; res.x = sa; res.y = sb;
    *(f32x2*)(outp + ((size_t)b*SEQ + r0 + m)*DIM + d) = res;
  }
}

// ---------------- Kernel B v1 (fallback when workspace is too small) --------------
__global__ __launch_bounds__(512,2) void kB_old(const float* __restrict__ q,
                                                const float* __restrict__ pos,
                                                const float* __restrict__ v,
                                                const float* __restrict__ M,
                                                float* __restrict__ outp,
                                                float* __restrict__ attn){
  extern __shared__ __align__(16) float smem[];
  float* S    = smem;
  float* VTM  = smem + VTM_OFF;
  u16*   vT   = (u16*)VTM;
  float* Tl   = smem + TL_OFF;
  float* qs   = smem + QS_OFF;
  float* red  = smem + RED_OFF;
  float* mrow = red + 128;
  float* linv = mrow + 16;

  const int blk   = blockIdx.x;
  const int xcd   = blk & 7;
  const int slot  = blk >> 3;
  const int b     = xcd*2 + (slot & 1);
  const int bslot = slot >> 1;
  const int tid   = threadIdx.x;
  const int lane  = tid & 63;
  const int w     = tid >> 6;
  const int quad  = lane >> 4;
  const int l16   = lane & 15;

  const float* pb = pos + (size_t)b*SEQ*DIM;
  const float* vb = v   + (size_t)b*SEQ*DIM;
  const float* qb = q   + (size_t)b*SEQ*DIM;
  const float* Mb = M   + (size_t)b*4096;

  for (int t = 0; t < 8; ++t){
    const int r0 = (bslot*8 + t) * 16;
    __syncthreads();
    {
      const f32x4* Mg = (const f32x4*)Mb;
      f32x4* Md = (f32x4*)VTM;
      Md[tid]     = Mg[tid];
      Md[tid+512] = Mg[tid+512];
      if (tid < 256)
        ((f32x4*)qs)[tid] = ((const f32x4*)(qb + (size_t)r0*DIM))[tid];
    }
    __syncthreads();
    {
      const int r = tid >> 5;
      const int e = tid & 31;
      float a0 = 0.f, a1 = 0.f;
      #pragma unroll 8
      for (int d=0; d<64; ++d){
        const float qd = qs[r*64 + d];
        a0 += qd * VTM[d*64 + e];
        a1 += qd * VTM[d*64 + e + 32];
      }
      Tl[r*64 + e]      = a0;
      Tl[r*64 + e + 32] = a1;
    }
    __syncthreads();
    bf16x8 Ah[2], Al[2];
    #pragma unroll
    for (int h=0; h<2; ++h){
      const float* ts = &Tl[l16*64 + h*32 + quad*8];
      split8(*(const f32x4*)ts, *(const f32x4*)(ts+4), Ah[h], Al[h]);
    }
    #pragma unroll 2
    for (int tt=0; tt<16; ++tt){
      const int c0 = w*256 + tt*16;
      const float* pr = pb + (size_t)(c0 + l16)*DIM + quad*8;
      f32x4 p0 = *(const f32x4*)pr;
      f32x4 p1 = *(const f32x4*)(pr+4);
      f32x4 p2 = *(const f32x4*)(pr+32);
      f32x4 p3 = *(const f32x4*)(pr+36);
      bf16x8 Bh0, Bl0, Bh1, Bl1;
      split8(p0, p1, Bh0, Bl0);
      split8(p2, p3, Bh1, Bl1);
      f32x4 acc = {0.f,0.f,0.f,0.f};
      acc = MFMA16(Ah[0], Bh0, acc, 0,0,0);
      acc = MFMA16(Al[0], Bh0, acc, 0,0,0);
      acc = MFMA16(Ah[0], Bl0, acc, 0,0,0);
      acc = MFMA16(Ah[1], Bh1, acc, 0,0,0);
      acc = MFMA16(Al[1], Bh1, acc, 0,0,0);
      acc = MFMA16(Ah[1], Bl1, acc, 0,0,0);
      #pragma unroll
      for (int i=0;i<4;i++)
        S[(quad*4+i)*SROW + c0 + l16] = acc[i];
    }
    __syncthreads();
    {
      const int r = tid & 15, seg = tid >> 4;
      const f32x4* sr = (const f32x4*)&S[r*SROW + seg*64];
      float m = -3.0e38f;
      #pragma unroll
      for (int i=0;i<16;i++){
        const f32x4 x = sr[i];
        m = fmaxf(m, fmaxf(fmaxf(x.x,x.y), fmaxf(x.z,x.w)));
      }
      m = fmaxf(m, __shfl_xor(m, 16, 64));
      m = fmaxf(m, __shfl_xor(m, 32, 64));
      if (lane < 16) red[w*16 + lane] = m;
    }
    __syncthreads();
    if (tid < 16){
      float m = red[tid];
      #pragma unroll
      for (int w2=1; w2<8; ++w2) m = fmaxf(m, red[w2*16 + tid]);
      mrow[tid] = m;
    }
    __syncthreads();
    {
      const int r = tid & 15, seg = tid >> 4;
      const float mr = mrow[r];
      f32x4* sr = (f32x4*)&S[r*SROW + seg*64];
      float s = 0.f;
      #pragma unroll
      for (int i=0;i<16;i++){
        f32x4 x = sr[i];
        x.x = __expf(x.x - mr); x.y = __expf(x.y - mr);
        x.z = __expf(x.z - mr); x.w = __expf(x.w - mr);
        sr[i] = x;
        s += x.x + x.y + x.z + x.w;
      }
      s += __shfl_xor(s, 16, 64);
      s += __shfl_xor(s, 32, 64);
      if (lane < 16) red[w*16 + lane] = s;
    }
    __syncthreads();
    if (tid < 16){
      float s = red[tid];
      #pragma unroll
      for (int w2=1; w2<8; ++w2) s += red[w2*16 + tid];
      linv[tid] = 1.0f / s;
    }
    __syncthreads();
    {
      const int r  = tid >> 5;
      const int cq = (tid & 31) * 4;
      const float li = linv[r];
      float* ab = attn + ((size_t)b*SEQ + r0 + r)*(size_t)SEQ;
      const float* sr = &S[r*SROW];
      #pragma unroll
      for (int j=0;j<16;++j){
        const int c = cq + 128*j;
        f32x4 val = *(const f32x4*)(sr + c);
        val.x *= li; val.y *= li; val.z *= li; val.w *= li;
        __builtin_nontemporal_store(val, (f32x4*)(ab + c));
      }
    }
    f32x4 pacc0 = {0.f,0.f,0.f,0.f}, pacc1 = {0.f,0.f,0.f,0.f};
    const int kch   = w >> 1;
    const int npair = w & 1;
    for (int vt2=0; vt2<16; ++vt2){
      __syncthreads();
      {
        const int c4 = (tid & 31)*4;
        const int d4 = (tid >> 5)*4;
        const int cg = vt2*128 + c4;
        f32x4 r0v = *(const f32x4*)(vb + (size_t)(cg  )*DIM + d4);
        f32x4 r1v = *(const f32x4*)(vb + (size_t)(cg+1)*DIM + d4);
        f32x4 r2v = *(const f32x4*)(vb + (size_t)(cg+2)*DIM + d4);
        f32x4 r3v = *(const f32x4*)(vb + (size_t)(cg+3)*DIM + d4);
        const float rr[4][4] = {{r0v.x,r1v.x,r2v.x,r3v.x},
                                {r0v.y,r1v.y,r2v.y,r3v.y},
                                {r0v.z,r1v.z,r2v.z,r3v.z},
                                {r0v.w,r1v.w,r2v.w,r3v.w}};
        #pragma unroll
        for (int dd=0; dd<4; ++dd){
          u16x4 pk;
          pk[0]=f2bf(rr[dd][0]); pk[1]=f2bf(rr[dd][1]);
          pk[2]=f2bf(rr[dd][2]); pk[3]=f2bf(rr[dd][3]);
          *(u16x4*)&vT[(d4+dd)*136 + c4] = pk;
        }
      }
      __syncthreads();
      {
        const int cbase = kch*32;
        const float* es = &S[l16*SROW + vt2*128 + cbase + quad*8];
        const bf16x8 Af = pack8(*(const f32x4*)es, *(const f32x4*)(es+4));
        const int n0 = (npair*2)*16 + l16;
        const int n1 = n0 + 16;
        const bf16x8 B0 = *(const bf16x8*)&vT[n0*136 + cbase + quad*8];
        const bf16x8 B1 = *(const bf16x8*)&vT[n1*136 + cbase + quad*8];
        pacc0 = MFMA16(Af, B0, pacc0, 0,0,0);
        pacc1 = MFMA16(Af, B1, pacc1, 0,0,0);
      }
    }
    __syncthreads();
    {
      float* Pf = S;
      #pragma unroll
      for (int i=0;i<4;i++){
        Pf[(w*2+0)*256 + (quad*4+i)*16 + l16] = pacc0[i];
        Pf[(w*2+1)*256 + (quad*4+i)*16 + l16] = pacc1[i];
      }
      pacc0 = (f32x4){0.f,0.f,0.f,0.f};
      pacc1 = (f32x4){0.f,0.f,0.f,0.f};
    }
    __syncthreads();
    {
      const int o = tid*2;
      const int m = o >> 6;
      const int d = o & 63;
      const int nt = d >> 4;
      float s0 = 0.f, s1 = 0.f;
      #pragma unroll
      for (int kk=0; kk<4; ++kk){
        const int sl = (2*kk + (nt>>1))*2 + (nt&1);
        s0 += S[sl*256 + m*16 + (d&15)];
        s1 += S[sl*256 + m*16 + (d&15) + 1];
      }
      const float li = linv[m];
      f32x2 res; res.x = s0*li; res.y = s1*li;
      *(f32x2*)(outp + ((size_t)b*SEQ + r0 + m)*DIM + d) = res;
    }
  }
}

extern "C" void kernel_launch(void* const* d_in, const int* in_sizes, int n_in,
                              void* d_out, int out_size, void* d_ws, size_t ws_size,
                              hipStream_t stream){
  const float* q = (const float*)d_in[0];
  const float* k = (const float*)d_in[1];
  const float* v = (const float*)d_in[2];
  const float* p = (const float*)d_in[3];
  float* out  = (float*)d_out;
  float* attn = out + OUT_ELEMS;          // second tuple element
  float* M    = (float*)d_ws;             // 16*64*64 fp32 = 256 KB
  float* part = attn;                     // M-partials scratch; dead after kA2

  // ws layout: M (256 KB) | posH (4 MB) | posL (4 MB) | vT (4 MB)
  const size_t NEED = 262144 + 3ull*BH*SEQ*DIM*sizeof(u16);  // 12.85 MB

  hipFuncSetAttribute((const void*)kB_old,
                      hipFuncAttributeMaxDynamicSharedMemorySize, LDS_BYTES);

  kA1<<<dim3(16,16), 256, 0, stream>>>(k, q, part);
  kA2<<<dim3(256),   256, 0, stream>>>(part, M);

  if (ws_size >= NEED){
    u16* posH = (u16*)((char*)d_ws + 262144);
    u16* posL = posH + (size_t)BH*SEQ*DIM;
    u16* vTg  = posL + (size_t)BH*SEQ*DIM;
    kP<<<dim3(16,16), 512, 0, stream>>>(p, v, posH, posL, vTg);
    kB10<<<dim3(2048), 512, 0, stream>>>(q, M, posH, posL, vTg, out, attn);
  } else {
    kB_old<<<dim3(256), 512, LDS_BYTES, stream>>>(q, p, v, M, out, attn);
  }
}

// Round 11
// 381.257 us; speedup vs baseline: 1.2914x; 1.2388x over previous
//
#include <hip/hip_runtime.h>
#include <cstdint>

#define BH  16
#define SEQ 2048
#define DIM 64
#define OUT_ELEMS (BH*SEQ*DIM)   // 2097152 floats; attn follows at this offset

typedef float f32x4 __attribute__((ext_vector_type(4)));
typedef float f32x2 __attribute__((ext_vector_type(2)));
typedef short bf16x8 __attribute__((ext_vector_type(8)));
typedef unsigned short u16;
typedef unsigned short u16x4 __attribute__((ext_vector_type(4)));

#define MFMA16 __builtin_amdgcn_mfma_f32_16x16x32_bf16

// ---- fallback-kernel LDS partition (kB_old) ----
#define SROW      2052
#define VTM_OFF   (16*SROW)
#define TL_OFF    (VTM_OFF + 4352)
#define QS_OFF    (TL_OFF + 1024)
#define RED_OFF   (QS_OFF + 1024)
#define LDS_FLOATS (RED_OFF + 160)
#define LDS_BYTES  (LDS_FLOATS*4)

__device__ __forceinline__ u16 f2bf(float x){            // RNE f32->bf16
  uint32_t u = __float_as_uint(x);
  return (u16)((u + 0x7fffu + ((u>>16)&1u)) >> 16);
}
__device__ __forceinline__ void split8(f32x4 a, f32x4 b, bf16x8& hi, bf16x8& lo){
  float v[8] = {a.x,a.y,a.z,a.w,b.x,b.y,b.z,b.w};
  #pragma unroll
  for (int i=0;i<8;i++){
    uint32_t u  = __float_as_uint(v[i]);
    uint32_t hb = u & 0xffff0000u;
    hi[i] = (short)(hb>>16);
    lo[i] = (short)f2bf(v[i] - __uint_as_float(hb));
  }
}
__device__ __forceinline__ bf16x8 pack8(f32x4 a, f32x4 b){
  bf16x8 r;
  r[0]=(short)f2bf(a.x); r[1]=(short)f2bf(a.y); r[2]=(short)f2bf(a.z); r[3]=(short)f2bf(a.w);
  r[4]=(short)f2bf(b.x); r[5]=(short)f2bf(b.y); r[6]=(short)f2bf(b.z); r[7]=(short)f2bf(b.w);
  return r;
}

// ---------------- Kernel A1: partial M = k^T q (per batch, per 128-row chunk) ------
__global__ __launch_bounds__(256) void kA1(const float* __restrict__ kk,
                                           const float* __restrict__ qq,
                                           float* __restrict__ part){
  __shared__ __align__(16) float kl[64][68];
  __shared__ __align__(16) float ql[64][68];
  const int b   = blockIdx.y;
  const int ch  = blockIdx.x;
  const int tid = threadIdx.x;
  const int j     = tid & 63;
  const int ibase = (tid >> 6) * 16;   // wave-uniform
  const int lrow  = tid >> 2;
  const int lcol  = (tid & 3) * 16;
  const float* kb = kk + (size_t)b*SEQ*DIM;
  const float* qb = qq + (size_t)b*SEQ*DIM;
  float acc[16];
  #pragma unroll
  for (int i=0;i<16;i++) acc[i]=0.f;
  for (int sub=0; sub<2; ++sub){
    const int l0 = ch*128 + sub*64;
    const f32x4* ks = (const f32x4*)(kb + (size_t)(l0+lrow)*DIM + lcol);
    const f32x4* qs = (const f32x4*)(qb + (size_t)(l0+lrow)*DIM + lcol);
    f32x4 kv[4], qv[4];
    #pragma unroll
    for (int i=0;i<4;i++){ kv[i]=ks[i]; qv[i]=qs[i]; }
    __syncthreads();
    #pragma unroll
    for (int i=0;i<4;i++){
      *(f32x4*)&kl[lrow][lcol+4*i] = kv[i];
      *(f32x4*)&ql[lrow][lcol+4*i] = qv[i];
    }
    __syncthreads();
    for (int t=0; t<64; ++t){
      const float qv1 = ql[t][j];
      const f32x4 k0 = *(const f32x4*)&kl[t][ibase];
      const f32x4 k1 = *(const f32x4*)&kl[t][ibase+4];
      const f32x4 k2 = *(const f32x4*)&kl[t][ibase+8];
      const f32x4 k3 = *(const f32x4*)&kl[t][ibase+12];
      acc[0]+=k0.x*qv1; acc[1]+=k0.y*qv1; acc[2]+=k0.z*qv1; acc[3]+=k0.w*qv1;
      acc[4]+=k1.x*qv1; acc[5]+=k1.y*qv1; acc[6]+=k1.z*qv1; acc[7]+=k1.w*qv1;
      acc[8]+=k2.x*qv1; acc[9]+=k2.y*qv1; acc[10]+=k2.z*qv1; acc[11]+=k2.w*qv1;
      acc[12]+=k3.x*qv1; acc[13]+=k3.y*qv1; acc[14]+=k3.z*qv1; acc[15]+=k3.w*qv1;
    }
  }
  float* pp = part + (size_t)(b*16+ch)*4096;
  #pragma unroll
  for (int ii=0; ii<16; ++ii)
    pp[(ibase+ii)*64 + j] = acc[ii];
}

// ---------------- Kernel A2: reduce partials, fold 1/temper^2 ----------------------
__global__ __launch_bounds__(256) void kA2(const float* __restrict__ part,
                                           float* __restrict__ M){
  const int idx = blockIdx.x*256 + threadIdx.x;
  const int b = idx >> 12, o = idx & 4095;
  float s = 0.f;
  #pragma unroll
  for (int ch=0; ch<16; ++ch)
    s += part[(size_t)(b*16+ch)*4096 + o];
  M[(size_t)b*4096 + o] = s * (1.0f/64.0f);
}

// ---------------- Kernel P: precondition operands, FRAGMENT-LINEAR layouts --------
// posH/posL frag layout: pHf[b][gt*2+half][lane*8+j] (1 KB per half-tile block)
//   = bf16 hi/lo of pos[b][gt*16 + (lane&15)][half*32 + (lane>>4)*8 + j]
// vT frag layout: vTf[b][(ktile*4+n)*512 + lane*8+j]
//   = bf16 of v[b][k = ktile*32 + (lane>>4)*8 + j][d = n*16 + (lane&15)]  (transposed)
// Every kB operand load becomes base + lane*16B: one contiguous 1 KB per wave.
__global__ __launch_bounds__(512) void kP(const float* __restrict__ pos,
                                          const float* __restrict__ v,
                                          u16* __restrict__ pHf,
                                          u16* __restrict__ pLf,
                                          u16* __restrict__ vTf){
  __shared__ u16 vt[64][136];
  const int b   = blockIdx.y;
  const int ch  = blockIdx.x;            // 128-row chunk
  const int tid = threadIdx.x;
  // ---- pos hi/lo planes, written in fragment order ----
  {
    const f32x4* pb = (const f32x4*)(pos + (size_t)b*SEQ*DIM + (size_t)ch*128*DIM);
    u16* pH = pHf + (size_t)b*SEQ*DIM;
    u16* pL = pLf + (size_t)b*SEQ*DIM;
    #pragma unroll
    for (int i=0;i<4;i++){
      const int idx = i*512 + tid;       // f32x4 index within chunk (0..2047)
      const f32x4 x = pb[idx];
      const float xs[4] = {x.x,x.y,x.z,x.w};
      u16x4 h, l;
      #pragma unroll
      for (int jj=0;jj<4;jj++){
        uint32_t u  = __float_as_uint(xs[jj]);
        uint32_t hb = u & 0xffff0000u;
        h[jj] = (u16)(hb>>16);
        l[jj] = f2bf(xs[jj] - __uint_as_float(hb));
      }
      const int e0   = idx*4;            // element within chunk
      const int row  = e0 >> 6;          // 0..127
      const int d0   = e0 & 63;
      const int grow = ch*128 + row;
      const int gt   = grow >> 4;        // global 16-col tile
      const int half = d0 >> 5;
      const int ln   = (grow & 15) + 16*((d0 & 31) >> 3);
      const int j    = d0 & 7;           // 0 or 4
      const size_t off = (size_t)(gt*2 + half)*512 + ln*8 + j;
      *(u16x4*)(pH + off) = h;
      *(u16x4*)(pL + off) = l;
    }
  }
  // ---- v[ch*128..+128)[64] -> vt[d][c] bf16 (register transpose) ----
  {
    const float* vb = v + (size_t)b*SEQ*DIM;
    const int c4 = (tid & 31)*4;
    const int d4 = (tid >> 5)*4;
    const int cg = ch*128 + c4;
    f32x4 r0v = *(const f32x4*)(vb + (size_t)(cg  )*DIM + d4);
    f32x4 r1v = *(const f32x4*)(vb + (size_t)(cg+1)*DIM + d4);
    f32x4 r2v = *(const f32x4*)(vb + (size_t)(cg+2)*DIM + d4);
    f32x4 r3v = *(const f32x4*)(vb + (size_t)(cg+3)*DIM + d4);
    const float rr[4][4] = {{r0v.x,r1v.x,r2v.x,r3v.x},
                            {r0v.y,r1v.y,r2v.y,r3v.y},
                            {r0v.z,r1v.z,r2v.z,r3v.z},
                            {r0v.w,r1v.w,r2v.w,r3v.w}};
    #pragma unroll
    for (int dd=0; dd<4; ++dd){
      u16x4 pk;
      pk[0]=f2bf(rr[dd][0]); pk[1]=f2bf(rr[dd][1]);
      pk[2]=f2bf(rr[dd][2]); pk[3]=f2bf(rr[dd][3]);
      *(u16x4*)&vt[d4+dd][c4] = pk;
    }
  }
  __syncthreads();
  // ---- frag-order copy-out ----
  {
    u16* vb2 = vTf + (size_t)b*SEQ*DIM;
    const int d    = tid >> 3;           // 0..63
    const int roff = (tid & 7)*16;       // 0..112
    #pragma unroll
    for (int kq=0; kq<4; ++kq){
      const int c     = roff + kq*4;     // within-chunk col, c&7 in {0,4}
      const int ktile = ch*4 + (c >> 5);
      const int n     = d >> 4;
      const int ln    = (d & 15) + 16*((c & 31) >> 3);
      const int j     = c & 7;
      vb2[(size_t)(ktile*4 + n)*512 + ln*8 + j + 0] = vt[d][c];   // u16x4 copy:
      *(u16x4*)&vb2[(size_t)(ktile*4 + n)*512 + ln*8 + j] = *(const u16x4*)&vt[d][c];
    }
  }
}

// ---------------- Kernel B v12: v8 structure + fragment-linear operand loads ------
// grid 2048, 512 threads, (512,4) = 128-reg budget (proven no-spill at v8).
// Identical math/sync to v8 (218 us, passed). Only change: every MFMA B-operand
// load is now lane-contiguous (base + lane*16B), 8 sequential 128-B lines per
// instruction instead of 16 scattered ones -> tests the TA/L1 line-throughput
// hypothesis for the ~220 us plateau.
#define BSTR 36                          // Buf row stride (floats)

__global__ __launch_bounds__(512,4) void kB12(const float* __restrict__ q,
                                              const float* __restrict__ M,
                                              const u16* __restrict__ pHf,
                                              const u16* __restrict__ pLf,
                                              const u16* __restrict__ vTf,
                                              float* __restrict__ outp,
                                              float* __restrict__ attn){
  __shared__ __align__(16) float Tl[16*68];                 //  4352 B
  __shared__ __align__(16) float Buf[8*16*BSTR];            // 18432 B
  __shared__ __align__(16) float Pp[8*16*68];               // 34816 B
  __shared__ float red_m[128], red_s[128], mrow[16], linv[16];

  const int blk  = blockIdx.x;
  const int xcd  = blk & 7;
  const int idx  = blk >> 3;              // 0..255
  const int b    = xcd*2 + (idx & 1);     // batch pinned to XCD for L2 locality
  const int task = idx >> 1;              // 0..127
  const int r0   = task*16;
  const int tid  = threadIdx.x;
  const int lane = tid & 63;
  const int w    = tid >> 6;              // 0..7
  const int quad = lane >> 4;
  const int l16  = lane & 15;

  const float* qb  = q   + (size_t)b*SEQ*DIM;
  const float* Mb  = M   + (size_t)b*4096;
  const u16*   pHb = pHf + (size_t)b*SEQ*DIM;
  const u16*   pLb = pLf + (size_t)b*SEQ*DIM;
  const u16*   vTb = vTf + (size_t)b*SEQ*DIM;

  // ---- T[16][64] = q[r0..r0+16) * M (reads from L2) ----
  {
    const int r = tid >> 5;
    const int e = tid & 31;
    const float* qr = qb + (size_t)(r0+r)*DIM;
    float a0=0.f, a1=0.f;
    #pragma unroll 8
    for (int d=0; d<64; ++d){
      const float qd = qr[d];
      a0 += qd * Mb[d*64 + e];
      a1 += qd * Mb[d*64 + e + 32];
    }
    Tl[r*68 + e]      = a0;
    Tl[r*68 + e + 32] = a1;
  }
  __syncthreads();                                          // barrier 1

  // ---- A-frags (T hi/lo) for both k-halves ----
  bf16x8 Ah[2], Al[2];
  #pragma unroll
  for (int h=0; h<2; ++h){
    const float* ts = &Tl[l16*68 + h*32 + quad*8];
    split8(*(const f32x4*)ts, *(const f32x4*)(ts+4), Ah[h], Al[h]);
  }

  // ---- logits into registers: wave w covers cols [w*256, w*256+256) ----
  f32x4 A[16];
  #pragma unroll
  for (int tt=0; tt<16; ++tt){
    const int gt = w*16 + tt;            // global 16-col tile
    const u16* hB = pHb + (size_t)(gt*2)*512 + lane*8;
    const u16* lB = pLb + (size_t)(gt*2)*512 + lane*8;
    const bf16x8 Bh0 = *(const bf16x8*)hB;
    const bf16x8 Bh1 = *(const bf16x8*)(hB + 512);
    const bf16x8 Bl0 = *(const bf16x8*)lB;
    const bf16x8 Bl1 = *(const bf16x8*)(lB + 512);
    f32x4 acc = {0.f,0.f,0.f,0.f};
    acc = MFMA16(Ah[0], Bh0, acc, 0,0,0);
    acc = MFMA16(Al[0], Bh0, acc, 0,0,0);
    acc = MFMA16(Ah[0], Bl0, acc, 0,0,0);
    acc = MFMA16(Ah[1], Bh1, acc, 0,0,0);
    acc = MFMA16(Al[1], Bh1, acc, 0,0,0);
    acc = MFMA16(Ah[1], Bl1, acc, 0,0,0);
    A[tt] = acc;
  }

  // ---- per-lane row stats (rows quad*4+i, exp computed ONCE) ----
  float mloc[4], sloc[4];
  #pragma unroll
  for (int i=0;i<4;++i) mloc[i] = A[0][i];
  #pragma unroll
  for (int tt=1; tt<16; ++tt){
    #pragma unroll
    for (int i=0;i<4;++i) mloc[i] = fmaxf(mloc[i], A[tt][i]);
  }
  #pragma unroll
  for (int i=0;i<4;++i) sloc[i] = 0.f;
  #pragma unroll
  for (int tt=0; tt<16; ++tt){
    #pragma unroll
    for (int i=0;i<4;++i){
      const float e = __expf(A[tt][i] - mloc[i]);
      A[tt][i] = e;
      sloc[i] += e;
    }
  }
  // cross-lane (l16) combine with rescale
  float mc[4], sc[4];
  #pragma unroll
  for (int i=0;i<4;++i){ mc[i]=mloc[i]; sc[i]=sloc[i]; }
  #pragma unroll
  for (int mk=1; mk<16; mk<<=1){
    #pragma unroll
    for (int i=0;i<4;++i){
      const float mo = __shfl_xor(mc[i], mk, 64);
      const float so = __shfl_xor(sc[i], mk, 64);
      const float t  = fmaxf(mc[i], mo);
      sc[i] = sc[i]*__expf(mc[i]-t) + so*__expf(mo-t);
      mc[i] = t;
    }
  }
  if (l16 == 0){
    #pragma unroll
    for (int i=0;i<4;++i){
      red_m[w*16 + quad*4 + i] = mc[i];
      red_s[w*16 + quad*4 + i] = sc[i];
    }
  }
  __syncthreads();                                          // barrier 2
  if (tid < 16){
    float m = red_m[tid], s = red_s[tid];
    #pragma unroll
    for (int w2=1; w2<8; ++w2){
      const float mo = red_m[w2*16 + tid], so = red_s[w2*16 + tid];
      const float t  = fmaxf(m, mo);
      s = s*__expf(m-t) + so*__expf(mo-t);
      m = t;
    }
    mrow[tid] = m;
    linv[tid] = 1.0f/s;
  }
  __syncthreads();                                          // barrier 3

  // ---- normalize in registers: A = exp(x - m_g) * linv ----
  #pragma unroll
  for (int i=0;i<4;++i){
    const float cf = __expf(mloc[i] - mrow[quad*4+i]) * linv[quad*4+i];
    #pragma unroll
    for (int tt=0; tt<16; ++tt) A[tt][i] *= cf;
  }

  // ---- fused attn-store + PV, per 32-col chunk, wave-private Buf ----
  f32x4 pa0={0.f,0.f,0.f,0.f}, pa1=pa0, pa2=pa0, pa3=pa0;
  float* bw = &Buf[w*16*BSTR];
  const int srow = lane >> 3;              // 0..7
  const int scol = (lane & 7)*4;           // 0..28
  float* abase = attn + ((size_t)b*SEQ + r0)*(size_t)SEQ;
  #pragma unroll
  for (int pr=0; pr<8; ++pr){
    // deposit 16x32 normalized chunk (cols pr*32..+32 of this wave's span)
    #pragma unroll
    for (int i=0;i<4;++i){
      bw[(quad*4+i)*BSTR      + l16] = A[2*pr  ][i];
      bw[(quad*4+i)*BSTR + 16 + l16] = A[2*pr+1][i];
    }
    // PV B-loads: fragment-linear, one contiguous 1 KB per instruction
    const int ktile = w*8 + pr;
    const u16* vb2 = vTb + (size_t)(ktile*4)*512 + lane*8;
    const bf16x8 B0 = *(const bf16x8*)vb2;
    const bf16x8 B1 = *(const bf16x8*)(vb2 + 512);
    const bf16x8 B2 = *(const bf16x8*)(vb2 + 1024);
    const bf16x8 B3 = *(const bf16x8*)(vb2 + 1536);
    asm volatile("s_waitcnt lgkmcnt(0)" ::: "memory");
    __builtin_amdgcn_sched_barrier(0);
    // PV A-frag: row l16, k = quad*8..+8
    const f32x4 fa0 = *(const f32x4*)&bw[l16*BSTR + quad*8];
    const f32x4 fa1 = *(const f32x4*)&bw[l16*BSTR + quad*8 + 4];
    const bf16x8 Af = pack8(fa0, fa1);
    const f32x4 st0 = *(const f32x4*)&bw[srow*BSTR + scol];
    const f32x4 st1 = *(const f32x4*)&bw[(srow+8)*BSTR + scol];
    // PV MFMAs first (B-frags have arrived by now), stores after
    pa0 = MFMA16(Af, B0, pa0, 0,0,0);
    pa1 = MFMA16(Af, B1, pa1, 0,0,0);
    pa2 = MFMA16(Af, B2, pa2, 0,0,0);
    pa3 = MFMA16(Af, B3, pa3, 0,0,0);
    // attn store: 8 lanes x f32x4 = one full 128-B line per row per instruction
    const int c0p = w*256 + pr*32;
    __builtin_nontemporal_store(st0, (f32x4*)(abase + (size_t)srow*SEQ     + c0p + scol));
    __builtin_nontemporal_store(st1, (f32x4*)(abase + (size_t)(srow+8)*SEQ + c0p + scol));
    asm volatile("" ::: "memory");        // keep next deposit after this chunk's reads
  }

  // ---- deposit per-wave PV partials, reduce across the 8 k-chunks ----
  {
    float* pp = &Pp[w*16*68];
    #pragma unroll
    for (int i=0;i<4;++i){
      pp[(quad*4+i)*68 +  0 + l16] = pa0[i];
      pp[(quad*4+i)*68 + 16 + l16] = pa1[i];
      pp[(quad*4+i)*68 + 32 + l16] = pa2[i];
      pp[(quad*4+i)*68 + 48 + l16] = pa3[i];
    }
  }
  __syncthreads();                                          // barrier 4
  {
    const int o = tid*2;
    const int m = o >> 6;
    const int d = o & 63;
    float sa=0.f, sb=0.f;
    #pragma unroll
    for (int kk=0; kk<8; ++kk){
      const float* pr2 = &Pp[kk*16*68 + m*68 + d];
      sa += pr2[0];
      sb += pr2[1];
    }
    f32x2 res; res.x = sa; res.y = sb;
    *(f32x2*)(outp + ((size_t)b*SEQ + r0 + m)*DIM + d) = res;
  }
}

// ---------------- Kernel B v1 (fallback when workspace is too small) --------------
__global__ __launch_bounds__(512,2) void kB_old(const float* __restrict__ q,
                                                const float* __restrict__ pos,
                                                const float* __restrict__ v,
                                                const float* __restrict__ M,
                                                float* __restrict__ outp,
                                                float* __restrict__ attn){
  extern __shared__ __align__(16) float smem[];
  float* S    = smem;
  float* VTM  = smem + VTM_OFF;
  u16*   vT   = (u16*)VTM;
  float* Tl   = smem + TL_OFF;
  float* qs   = smem + QS_OFF;
  float* red  = smem + RED_OFF;
  float* mrow = red + 128;
  float* linv = mrow + 16;

  const int blk   = blockIdx.x;
  const int xcd   = blk & 7;
  const int slot  = blk >> 3;
  const int b     = xcd*2 + (slot & 1);
  const int bslot = slot >> 1;
  const int tid   = threadIdx.x;
  const int lane  = tid & 63;
  const int w     = tid >> 6;
  const int quad  = lane >> 4;
  const int l16   = lane & 15;

  const float* pb = pos + (size_t)b*SEQ*DIM;
  const float* vb = v   + (size_t)b*SEQ*DIM;
  const float* qb = q   + (size_t)b*SEQ*DIM;
  const float* Mb = M   + (size_t)b*4096;

  for (int t = 0; t < 8; ++t){
    const int r0 = (bslot*8 + t) * 16;
    __syncthreads();
    {
      const f32x4* Mg = (const f32x4*)Mb;
      f32x4* Md = (f32x4*)VTM;
      Md[tid]     = Mg[tid];
      Md[tid+512] = Mg[tid+512];
      if (tid < 256)
        ((f32x4*)qs)[tid] = ((const f32x4*)(qb + (size_t)r0*DIM))[tid];
    }
    __syncthreads();
    {
      const int r = tid >> 5;
      const int e = tid & 31;
      float a0 = 0.f, a1 = 0.f;
      #pragma unroll 8
      for (int d=0; d<64; ++d){
        const float qd = qs[r*64 + d];
        a0 += qd * VTM[d*64 + e];
        a1 += qd * VTM[d*64 + e + 32];
      }
      Tl[r*64 + e]      = a0;
      Tl[r*64 + e + 32] = a1;
    }
    __syncthreads();
    bf16x8 Ah[2], Al[2];
    #pragma unroll
    for (int h=0; h<2; ++h){
      const float* ts = &Tl[l16*64 + h*32 + quad*8];
      split8(*(const f32x4*)ts, *(const f32x4*)(ts+4), Ah[h], Al[h]);
    }
    #pragma unroll 2
    for (int tt=0; tt<16; ++tt){
      const int c0 = w*256 + tt*16;
      const float* pr = pb + (size_t)(c0 + l16)*DIM + quad*8;
      f32x4 p0 = *(const f32x4*)pr;
      f32x4 p1 = *(const f32x4*)(pr+4);
      f32x4 p2 = *(const f32x4*)(pr+32);
      f32x4 p3 = *(const f32x4*)(pr+36);
      bf16x8 Bh0, Bl0, Bh1, Bl1;
      split8(p0, p1, Bh0, Bl0);
      split8(p2, p3, Bh1, Bl1);
      f32x4 acc = {0.f,0.f,0.f,0.f};
      acc = MFMA16(Ah[0], Bh0, acc, 0,0,0);
      acc = MFMA16(Al[0], Bh0, acc, 0,0,0);
      acc = MFMA16(Ah[0], Bl0, acc, 0,0,0);
      acc = MFMA16(Ah[1], Bh1, acc, 0,0,0);
      acc = MFMA16(Al[1], Bh1, acc, 0,0,0);
      acc = MFMA16(Ah[1], Bl1, acc, 0,0,0);
      #pragma unroll
      for (int i=0;i<4;i++)
        S[(quad*4+i)*SROW + c0 + l16] = acc[i];
    }
    __syncthreads();
    {
      const int r = tid & 15, seg = tid >> 4;
      const f32x4* sr = (const f32x4*)&S[r*SROW + seg*64];
      float m = -3.0e38f;
      #pragma unroll
      for (int i=0;i<16;i++){
        const f32x4 x = sr[i];
        m = fmaxf(m, fmaxf(fmaxf(x.x,x.y), fmaxf(x.z,x.w)));
      }
      m = fmaxf(m, __shfl_xor(m, 16, 64));
      m = fmaxf(m, __shfl_xor(m, 32, 64));
      if (lane < 16) red[w*16 + lane] = m;
    }
    __syncthreads();
    if (tid < 16){
      float m = red[tid];
      #pragma unroll
      for (int w2=1; w2<8; ++w2) m = fmaxf(m, red[w2*16 + tid]);
      mrow[tid] = m;
    }
    __syncthreads();
    {
      const int r = tid & 15, seg = tid >> 4;
      const float mr = mrow[r];
      f32x4* sr = (f32x4*)&S[r*SROW + seg*64];
      float s = 0.f;
      #pragma unroll
      for (int i=0;i<16;i++){
        f32x4 x = sr[i];
        x.x = __expf(x.x - mr); x.y = __expf(x.y - mr);
        x.z = __expf(x.z - mr); x.w = __expf(x.w - mr);
        sr[i] = x;
        s += x.x + x.y + x.z + x.w;
      }
      s += __shfl_xor(s, 16, 64);
      s += __shfl_xor(s, 32, 64);
      if (lane < 16) red[w*16 + lane] = s;
    }
    __syncthreads();
    if (tid < 16){
      float s = red[tid];
      #pragma unroll
      for (int w2=1; w2<8; ++w2) s += red[w2*16 + tid];
      linv[tid] = 1.0f / s;
    }
    __syncthreads();
    {
      const int r  = tid >> 5;
      const int cq = (tid & 31) * 4;
      const float li = linv[r];
      float* ab = attn + ((size_t)b*SEQ + r0 + r)*(size_t)SEQ;
      const float* sr = &S[r*SROW];
      #pragma unroll
      for (int j=0;j<16;++j){
        const int c = cq + 128*j;
        f32x4 val = *(const f32x4*)(sr + c);
        val.x *= li; val.y *= li; val.z *= li; val.w *= li;
        __builtin_nontemporal_store(val, (f32x4*)(ab + c));
      }
    }
    f32x4 pacc0 = {0.f,0.f,0.f,0.f}, pacc1 = {0.f,0.f,0.f,0.f};
    const int kch   = w >> 1;
    const int npair = w & 1;
    for (int vt2=0; vt2<16; ++vt2){
      __syncthreads();
      {
        const int c4 = (tid & 31)*4;
        const int d4 = (tid >> 5)*4;
        const int cg = vt2*128 + c4;
        f32x4 r0v = *(const f32x4*)(vb + (size_t)(cg  )*DIM + d4);
        f32x4 r1v = *(const f32x4*)(vb + (size_t)(cg+1)*DIM + d4);
        f32x4 r2v = *(const f32x4*)(vb + (size_t)(cg+2)*DIM + d4);
        f32x4 r3v = *(const f32x4*)(vb + (size_t)(cg+3)*DIM + d4);
        const float rr[4][4] = {{r0v.x,r1v.x,r2v.x,r3v.x},
                                {r0v.y,r1v.y,r2v.y,r3v.y},
                                {r0v.z,r1v.z,r2v.z,r3v.z},
                                {r0v.w,r1v.w,r2v.w,r3v.w}};
        #pragma unroll
        for (int dd=0; dd<4; ++dd){
          u16x4 pk;
          pk[0]=f2bf(rr[dd][0]); pk[1]=f2bf(rr[dd][1]);
          pk[2]=f2bf(rr[dd][2]); pk[3]=f2bf(rr[dd][3]);
          *(u16x4*)&vT[(d4+dd)*136 + c4] = pk;
        }
      }
      __syncthreads();
      {
        const int cbase = kch*32;
        const float* es = &S[l16*SROW + vt2*128 + cbase + quad*8];
        const bf16x8 Af = pack8(*(const f32x4*)es, *(const f32x4*)(es+4));
        const int n0 = (npair*2)*16 + l16;
        const int n1 = n0 + 16;
        const bf16x8 B0 = *(const bf16x8*)&vT[n0*136 + cbase + quad*8];
        const bf16x8 B1 = *(const bf16x8*)&vT[n1*136 + cbase + quad*8];
        pacc0 = MFMA16(Af, B0, pacc0, 0,0,0);
        pacc1 = MFMA16(Af, B1, pacc1, 0,0,0);
      }
    }
    __syncthreads();
    {
      float* Pf = S;
      #pragma unroll
      for (int i=0;i<4;i++){
        Pf[(w*2+0)*256 + (quad*4+i)*16 + l16] = pacc0[i];
        Pf[(w*2+1)*256 + (quad*4+i)*16 + l16] = pacc1[i];
      }
      pacc0 = (f32x4){0.f,0.f,0.f,0.f};
      pacc1 = (f32x4){0.f,0.f,0.f,0.f};
    }
    __syncthreads();
    {
      const int o = tid*2;
      const int m = o >> 6;
      const int d = o & 63;
      const int nt = d >> 4;
      float s0 = 0.f, s1 = 0.f;
      #pragma unroll
      for (int kk=0; kk<4; ++kk){
        const int sl = (2*kk + (nt>>1))*2 + (nt&1);
        s0 += S[sl*256 + m*16 + (d&15)];
        s1 += S[sl*256 + m*16 + (d&15) + 1];
      }
      const float li = linv[m];
      f32x2 res; res.x = s0*li; res.y = s1*li;
      *(f32x2*)(outp + ((size_t)b*SEQ + r0 + m)*DIM + d) = res;
    }
  }
}

extern "C" void kernel_launch(void* const* d_in, const int* in_sizes, int n_in,
                              void* d_out, int out_size, void* d_ws, size_t ws_size,
                              hipStream_t stream){
  const float* q = (const float*)d_in[0];
  const float* k = (const float*)d_in[1];
  const float* v = (const float*)d_in[2];
  const float* p = (const float*)d_in[3];
  float* out  = (float*)d_out;
  float* attn = out + OUT_ELEMS;          // second tuple element
  float* M    = (float*)d_ws;             // 16*64*64 fp32 = 256 KB
  float* part = attn;                     // M-partials scratch; dead after kA2

  // ws layout: M (256 KB) | pHf (4 MB) | pLf (4 MB) | vTf (4 MB)
  const size_t NEED = 262144 + 3ull*BH*SEQ*DIM*sizeof(u16);  // 12.85 MB

  hipFuncSetAttribute((const void*)kB_old,
                      hipFuncAttributeMaxDynamicSharedMemorySize, LDS_BYTES);

  kA1<<<dim3(16,16), 256, 0, stream>>>(k, q, part);
  kA2<<<dim3(256),   256, 0, stream>>>(part, M);

  if (ws_size >= NEED){
    u16* pHf = (u16*)((char*)d_ws + 262144);
    u16* pLf = pHf + (size_t)BH*SEQ*DIM;
    u16* vTf = pLf + (size_t)BH*SEQ*DIM;
    kP<<<dim3(16,16), 512, 0, stream>>>(p, v, pHf, pLf, vTf);
    kB12<<<dim3(2048), 512, 0, stream>>>(q, M, pHf, pLf, vTf, out, attn);
  } else {
    kB_old<<<dim3(256), 512, LDS_BYTES, stream>>>(q, p, v, M, out, attn);
  }
}